// Round 1
// baseline (295.528 us; speedup 1.0000x reference)
//
#include <hip/hip_runtime.h>

#define EMBED 128
#define NPATH 32
#define BATCH 4096
#define DIN 768
#define C1 128
#define C2 32

__device__ __forceinline__ float sel3(float a0, float a1, float a2, int m) {
    float r = a0;
    r = (m == 1) ? a1 : r;
    r = (m == 2) ? a2 : r;
    return r;
}

// One block per (b); template L = path length; gcol = group*256 column offset.
// Thread d (0..127) owns embedding dim d.
template<int L>
__global__ __launch_bounds__(128) void group_kernel(
    const int* __restrict__ ent, const int* __restrict__ mid,
    const float* __restrict__ counts, const float* __restrict__ E,
    const float* __restrict__ W, const float* __restrict__ Bm,
    float* __restrict__ h, int gcol)
{
    const int b = blockIdx.x;
    const int d = threadIdx.x;

    // Stage W/Bm rows (3 metapaths) in registers.
    const float W0 = W[0 * EMBED + d], W1r = W[1 * EMBED + d], W2r = W[2 * EMBED + d];
    const float B0 = Bm[0 * EMBED + d], B1 = Bm[1 * EMBED + d], B2 = Bm[2 * EMBED + d];

    const int* entb = ent + (size_t)b * NPATH * (L + 1);
    const int* midb = mid + (size_t)b * NPATH * L;
    const float* cb = counts + (size_t)b * NPATH;

    float num1 = 0.f, num2 = 0.f, den = 0.f;

    for (int p = 0; p < NPATH; ++p) {
        const float c = cb[p];

        int ei[L + 1];
        int mi[L];
#pragma unroll
        for (int i = 0; i <= L; ++i) ei[i] = entb[p * (L + 1) + i];
#pragma unroll
        for (int i = 0; i < L; ++i) mi[i] = midb[p * L + i];

        // Issue all embedding row loads up front (independent -> ILP).
        float e[L + 1];
#pragma unroll
        for (int i = 0; i <= L; ++i) e[i] = E[(size_t)ei[i] * EMBED + d];

        // forward chain
        float x = e[0];
#pragma unroll
        for (int i = 0; i < L; ++i) {
            const float wm = sel3(W0, W1r, W2r, mi[i]);
            const float bm = sel3(B0, B1, B2, mi[i]);
            x = fmaf(x * wm, e[i + 1], bm);
            x = fmaxf(x, 0.f);
        }
        const float out1 = x;

        // backward chain: y is stale = E[ent_L]
        const float yl = e[L];
        float x2 = yl;
#pragma unroll
        for (int i = L - 1; i >= 0; --i) {
            const float wm = sel3(W0, W1r, W2r, mi[i]);
            const float bm = sel3(B0, B1, B2, mi[i]);
            x2 = fmaf(x2 * wm, yl, bm);
            x2 = fmaxf(x2, 0.f);
        }

        num1 += c * out1;
        num2 += c * x2;
        den += c;
    }

    const float inv = 1.f / den;
    float* hb = h + (size_t)b * DIN + gcol;
    hb[d] = num1 * inv;
    hb[EMBED + d] = num2 * inv;
}

// Fused 3-layer MLP head. ROWS batch rows per block; thread = layer-1 column.
#define ROWS 8
__global__ __launch_bounds__(128) void mlp_kernel(
    const float* __restrict__ h,
    const float* __restrict__ W1, const float* __restrict__ b1,
    const float* __restrict__ W2, const float* __restrict__ b2,
    const float* __restrict__ W3, const float* __restrict__ b3,
    float* __restrict__ out)
{
    const int c = threadIdx.x;            // 0..127
    const int row0 = blockIdx.x * ROWS;

    float acc[ROWS];
    const float bias1 = b1[c];
#pragma unroll
    for (int r = 0; r < ROWS; ++r) acc[r] = bias1;

    const float* hb = h + (size_t)row0 * DIN;   // wave-uniform addresses -> scalar loads
#pragma unroll 4
    for (int k = 0; k < DIN; ++k) {
        const float w = W1[k * C1 + c];         // coalesced across threads
#pragma unroll
        for (int r = 0; r < ROWS; ++r)
            acc[r] = fmaf(hb[r * DIN + k], w, acc[r]);
    }

    __shared__ float h1[ROWS][C1];
#pragma unroll
    for (int r = 0; r < ROWS; ++r) h1[r][c] = fmaxf(acc[r], 0.f);
    __syncthreads();

    // layer 2: ROWS x 32 outputs, 128 threads -> each does ROWS/4 outputs
    __shared__ float h2[ROWS][C2];
    {
        const int c2 = c & 31;
        const int r0 = c >> 5;               // 0..3
        const float bias2 = b2[c2];
#pragma unroll
        for (int rr = 0; rr < ROWS; rr += 4) {
            const int r = r0 + rr;
            float a = bias2;
#pragma unroll
            for (int k = 0; k < C1; ++k)
                a = fmaf(h1[r][k], W2[k * C2 + c2], a);
            h2[r][c2] = fmaxf(a, 0.f);
        }
    }
    __syncthreads();

    // layer 3: one thread per row
    if (c < ROWS) {
        float a = b3[0];
#pragma unroll
        for (int k = 0; k < C2; ++k)
            a = fmaf(h2[c][k], W3[k], a);
        out[row0 + c] = a;
    }
}

extern "C" void kernel_launch(void* const* d_in, const int* in_sizes, int n_in,
                              void* d_out, int out_size, void* d_ws, size_t ws_size,
                              hipStream_t stream) {
    // setup_inputs() dict order:
    // 0:ent1 1:mid1 2:counts1 3:ent2 4:mid2 5:counts2 6:ent3 7:mid3 8:counts3
    // 9:E 10:W 11:Bm 12:W1 13:b1 14:W2 15:b2 16:W3 17:b3
    const int*   ent1 = (const int*)d_in[0];
    const int*   mid1 = (const int*)d_in[1];
    const float* cnt1 = (const float*)d_in[2];
    const int*   ent2 = (const int*)d_in[3];
    const int*   mid2 = (const int*)d_in[4];
    const float* cnt2 = (const float*)d_in[5];
    const int*   ent3 = (const int*)d_in[6];
    const int*   mid3 = (const int*)d_in[7];
    const float* cnt3 = (const float*)d_in[8];
    const float* E    = (const float*)d_in[9];
    const float* W    = (const float*)d_in[10];
    const float* Bm   = (const float*)d_in[11];
    const float* W1   = (const float*)d_in[12];
    const float* b1   = (const float*)d_in[13];
    const float* W2   = (const float*)d_in[14];
    const float* b2   = (const float*)d_in[15];
    const float* W3   = (const float*)d_in[16];
    const float* b3   = (const float*)d_in[17];

    float* h = (float*)d_ws;            // [BATCH, 768] intermediate, 12.6 MB
    float* out = (float*)d_out;

    group_kernel<1><<<BATCH, 128, 0, stream>>>(ent1, mid1, cnt1, E, W, Bm, h, 0);
    group_kernel<2><<<BATCH, 128, 0, stream>>>(ent2, mid2, cnt2, E, W, Bm, h, 256);
    group_kernel<3><<<BATCH, 128, 0, stream>>>(ent3, mid3, cnt3, E, W, Bm, h, 512);

    mlp_kernel<<<BATCH / ROWS, 128, 0, stream>>>(h, W1, b1, W2, b2, W3, b3, out);
}

// Round 2
// 270.190 us; speedup vs baseline: 1.0938x; 1.0938x over previous
//
#include <hip/hip_runtime.h>

#define EMBED 128
#define NPATH 32
#define BATCH 4096
#define DIN 768
#define C1 128
#define C2 32

__device__ __forceinline__ float sel3(float a0, float a1, float a2, int m) {
    float r = a0;
    r = (m == 1) ? a1 : r;
    r = (m == 2) ? a2 : r;
    return r;
}

__device__ __forceinline__ float4 sel3q(const float4 a[3], int m) {
    float4 r;
    r.x = sel3(a[0].x, a[1].x, a[2].x, m);
    r.y = sel3(a[0].y, a[1].y, a[2].y, m);
    r.z = sel3(a[0].z, a[1].z, a[2].z, m);
    r.w = sel3(a[0].w, a[1].w, a[2].w, m);
    return r;
}

// r = relu(x*wm*y + bm), componentwise, fma ordering identical to round-0 (bit-exact pass)
__device__ __forceinline__ float4 chain_step(float4 x, float4 y, float4 wm, float4 bm) {
    float4 r;
    r.x = fmaxf(fmaf(x.x * wm.x, y.x, bm.x), 0.f);
    r.y = fmaxf(fmaf(x.y * wm.y, y.y, bm.y), 0.f);
    r.z = fmaxf(fmaf(x.z * wm.z, y.z, bm.z), 0.f);
    r.w = fmaxf(fmaf(x.w * wm.w, y.w, bm.w), 0.f);
    return r;
}

// One block per (b, group). 256 threads: dl = tid&31 owns dims 4*dl..4*dl+3 (float4),
// pq = tid>>5 (0..7) owns paths p = pq, pq+8, pq+16, pq+24.
template<int L>
__device__ __forceinline__ void group_body(
    const int* __restrict__ ent, const int* __restrict__ mid,
    const float* __restrict__ counts, const float4* __restrict__ E4,
    const float4* __restrict__ W4, const float4* __restrict__ B4,
    float* __restrict__ h, int gcol, int* s_idx, float4* s_red)
{
    const int b = blockIdx.x;
    const int tid = threadIdx.x;
    const int dl = tid & 31;
    const int pq = tid >> 5;

    int* s_ent = s_idx;                                  // NPATH*(L+1)
    int* s_mid = s_idx + NPATH * (L + 1);                // NPATH*L
    float* s_cnt = (float*)(s_idx + NPATH * (2 * L + 1)); // NPATH

    // Bulk-stage indices & counts (coalesced, once) — removes index-load latency
    // from the per-path dependent chain.
    const int* entb = ent + (size_t)b * (NPATH * (L + 1));
    const int* midb = mid + (size_t)b * (NPATH * L);
    for (int i = tid; i < NPATH * (L + 1); i += 256) s_ent[i] = entb[i];
    for (int i = tid; i < NPATH * L; i += 256) s_mid[i] = midb[i];
    if (tid < NPATH) s_cnt[tid] = counts[(size_t)b * NPATH + tid];
    __syncthreads();

    // W/Bm quads in registers (24 VGPRs)
    float4 Wr[3], Br[3];
#pragma unroll
    for (int m = 0; m < 3; ++m) {
        Wr[m] = W4[m * 32 + dl];
        Br[m] = B4[m * 32 + dl];
    }

    float4 n1 = make_float4(0.f, 0.f, 0.f, 0.f);
    float4 n2 = make_float4(0.f, 0.f, 0.f, 0.f);

#pragma unroll 2
    for (int j = 0; j < NPATH / 8; ++j) {
        const int p = pq + 8 * j;
        int ei[L + 1], mi[L];
#pragma unroll
        for (int i = 0; i <= L; ++i) ei[i] = s_ent[p * (L + 1) + i];
#pragma unroll
        for (int i = 0; i < L; ++i) mi[i] = s_mid[p * L + i];

        // all gathers for this path issued up front (16 B/lane, 1 KB/wave-inst)
        float4 e[L + 1];
#pragma unroll
        for (int i = 0; i <= L; ++i) e[i] = E4[(size_t)ei[i] * 32 + dl];
        const float c = s_cnt[p];

        // forward
        float4 x = e[0];
#pragma unroll
        for (int i = 0; i < L; ++i)
            x = chain_step(x, e[i + 1], sel3q(Wr, mi[i]), sel3q(Br, mi[i]));

        // backward: y stale = E[ent_L]
        const float4 yl = e[L];
        float4 x2 = yl;
#pragma unroll
        for (int i = L - 1; i >= 0; --i)
            x2 = chain_step(x2, yl, sel3q(Wr, mi[i]), sel3q(Br, mi[i]));

        n1.x = fmaf(c, x.x, n1.x); n1.y = fmaf(c, x.y, n1.y);
        n1.z = fmaf(c, x.z, n1.z); n1.w = fmaf(c, x.w, n1.w);
        n2.x = fmaf(c, x2.x, n2.x); n2.y = fmaf(c, x2.y, n2.y);
        n2.z = fmaf(c, x2.z, n2.z); n2.w = fmaf(c, x2.w, n2.w);
    }

    // reduce over the 8 path-groups
    s_red[(pq * 2 + 0) * 32 + dl] = n1;
    s_red[(pq * 2 + 1) * 32 + dl] = n2;
    __syncthreads();
    if (tid < 64) {
        const int half = tid >> 5, dq = tid & 31;
        float4 a = s_red[(0 * 2 + half) * 32 + dq];
#pragma unroll
        for (int q = 1; q < 8; ++q) {
            float4 t = s_red[(q * 2 + half) * 32 + dq];
            a.x += t.x; a.y += t.y; a.z += t.z; a.w += t.w;
        }
        float den = 0.f;
#pragma unroll
        for (int p = 0; p < NPATH; ++p) den += s_cnt[p];
        const float inv = 1.f / den;
        a.x *= inv; a.y *= inv; a.z *= inv; a.w *= inv;
        float4* hb = (float4*)(h + (size_t)b * DIN + gcol);
        hb[half * 32 + dq] = a;
    }
}

__global__ __launch_bounds__(256) void groups_kernel(
    const int* __restrict__ e1, const int* __restrict__ m1, const float* __restrict__ c1,
    const int* __restrict__ e2, const int* __restrict__ m2, const float* __restrict__ c2,
    const int* __restrict__ e3, const int* __restrict__ m3, const float* __restrict__ c3,
    const float* __restrict__ E, const float* __restrict__ W, const float* __restrict__ Bm,
    float* __restrict__ h)
{
    __shared__ int s_idx[NPATH * 7 + NPATH];      // max(L=3): 128+96+32 ints
    __shared__ float4 s_red[8 * 2 * 32];          // 8 KB
    const float4* E4 = (const float4*)E;
    const float4* W4 = (const float4*)W;
    const float4* B4 = (const float4*)Bm;
    const int g = blockIdx.y;
    if (g == 0)      group_body<1>(e1, m1, c1, E4, W4, B4, h, 0,   s_idx, s_red);
    else if (g == 1) group_body<2>(e2, m2, c2, E4, W4, B4, h, 256, s_idx, s_red);
    else             group_body<3>(e3, m3, c3, E4, W4, B4, h, 512, s_idx, s_red);
}

// Fused MLP head. 16 rows/block, 256 threads: c = tid&127 (layer-1 col),
// rh = tid>>7 owns 8 rows. h row values are wave-uniform -> scalar (s_load) ops.
#define MROWS 16
__global__ __launch_bounds__(256) void mlp_kernel(
    const float* __restrict__ h,
    const float* __restrict__ W1, const float* __restrict__ b1,
    const float* __restrict__ W2, const float* __restrict__ b2,
    const float* __restrict__ W3, const float* __restrict__ b3,
    float* __restrict__ out)
{
    const int tid = threadIdx.x;
    const int c = tid & 127;
    const int rh = tid >> 7;                  // 0..1
    const int row0 = blockIdx.x * MROWS;

    float acc[8];
    const float bias1 = b1[c];
#pragma unroll
    for (int r = 0; r < 8; ++r) acc[r] = bias1;

    const float* h0 = h + (size_t)(row0 + rh * 8) * DIN;
    for (int k0 = 0; k0 < DIN; k0 += 8) {
        float w[8];
#pragma unroll
        for (int j = 0; j < 8; ++j) w[j] = W1[(k0 + j) * C1 + c];   // coalesced
#pragma unroll
        for (int r = 0; r < 8; ++r) {
#pragma unroll
            for (int j = 0; j < 8; ++j)
                acc[r] = fmaf(h0[r * DIN + k0 + j], w[j], acc[r]); // uniform -> s_load_dwordx8
        }
    }

    __shared__ float h1[MROWS][C1];
#pragma unroll
    for (int r = 0; r < 8; ++r) h1[rh * 8 + r][c] = fmaxf(acc[r], 0.f);
    __syncthreads();

    // layer 2: 16 rows x 32 cols = 512 outputs, 2 per thread
    __shared__ float h2[MROWS][C2];
    {
        const int r0 = tid >> 5;              // 0..7
        const int c2 = tid & 31;
        const float bias2 = b2[c2];
#pragma unroll
        for (int rr = 0; rr < MROWS; rr += 8) {
            const int r = r0 + rr;
            float a = bias2;
#pragma unroll
            for (int k = 0; k < C1; ++k)
                a = fmaf(h1[r][k], W2[k * C2 + c2], a);
            h2[r][c2] = fmaxf(a, 0.f);
        }
    }
    __syncthreads();

    // layer 3
    if (tid < MROWS) {
        float a = b3[0];
#pragma unroll
        for (int k = 0; k < C2; ++k)
            a = fmaf(h2[tid][k], W3[k], a);
        out[row0 + tid] = a;
    }
}

extern "C" void kernel_launch(void* const* d_in, const int* in_sizes, int n_in,
                              void* d_out, int out_size, void* d_ws, size_t ws_size,
                              hipStream_t stream) {
    const int*   ent1 = (const int*)d_in[0];
    const int*   mid1 = (const int*)d_in[1];
    const float* cnt1 = (const float*)d_in[2];
    const int*   ent2 = (const int*)d_in[3];
    const int*   mid2 = (const int*)d_in[4];
    const float* cnt2 = (const float*)d_in[5];
    const int*   ent3 = (const int*)d_in[6];
    const int*   mid3 = (const int*)d_in[7];
    const float* cnt3 = (const float*)d_in[8];
    const float* E    = (const float*)d_in[9];
    const float* W    = (const float*)d_in[10];
    const float* Bm   = (const float*)d_in[11];
    const float* W1   = (const float*)d_in[12];
    const float* b1   = (const float*)d_in[13];
    const float* W2   = (const float*)d_in[14];
    const float* b2   = (const float*)d_in[15];
    const float* W3   = (const float*)d_in[16];
    const float* b3   = (const float*)d_in[17];

    float* h = (float*)d_ws;   // [BATCH, 768]
    float* out = (float*)d_out;

    dim3 ggrid(BATCH, 3);
    groups_kernel<<<ggrid, 256, 0, stream>>>(ent1, mid1, cnt1, ent2, mid2, cnt2,
                                             ent3, mid3, cnt3, E, W, Bm, h);
    mlp_kernel<<<BATCH / MROWS, 256, 0, stream>>>(h, W1, b1, W2, b2, W3, b3, out);
}

// Round 3
// 213.895 us; speedup vs baseline: 1.3816x; 1.2632x over previous
//
#include <hip/hip_runtime.h>

#define EMBED 128
#define NPATH 32
#define BATCH 4096
#define DIN 768
#define C1 128
#define C2 32

__device__ __forceinline__ float sel3(float a0, float a1, float a2, int m) {
    float r = a0;
    r = (m == 1) ? a1 : r;
    r = (m == 2) ? a2 : r;
    return r;
}

__device__ __forceinline__ float4 sel3q(const float4 a[3], int m) {
    float4 r;
    r.x = sel3(a[0].x, a[1].x, a[2].x, m);
    r.y = sel3(a[0].y, a[1].y, a[2].y, m);
    r.z = sel3(a[0].z, a[1].z, a[2].z, m);
    r.w = sel3(a[0].w, a[1].w, a[2].w, m);
    return r;
}

__device__ __forceinline__ float4 chain_step(float4 x, float4 y, float4 wm, float4 bm) {
    float4 r;
    r.x = fmaxf(fmaf(x.x * wm.x, y.x, bm.x), 0.f);
    r.y = fmaxf(fmaf(x.y * wm.y, y.y, bm.y), 0.f);
    r.z = fmaxf(fmaf(x.z * wm.z, y.z, bm.z), 0.f);
    r.w = fmaxf(fmaf(x.w * wm.w, y.w, bm.w), 0.f);
    return r;
}

// One block per (b, group). 256 threads: dl = tid&31 owns dims 4*dl..4*dl+3 (float4),
// pq = tid>>5 (0..7) owns paths p = pq, pq+8, pq+16, pq+24.
template<int L>
__device__ __forceinline__ void group_body(
    const int* __restrict__ ent, const int* __restrict__ mid,
    const float* __restrict__ counts, const float4* __restrict__ E4,
    const float4* __restrict__ W4, const float4* __restrict__ B4,
    float* __restrict__ h, int gcol, int* s_idx, float4* s_red)
{
    const int b = blockIdx.x;
    const int tid = threadIdx.x;
    const int dl = tid & 31;
    const int pq = tid >> 5;

    int* s_ent = s_idx;
    int* s_mid = s_idx + NPATH * (L + 1);
    float* s_cnt = (float*)(s_idx + NPATH * (2 * L + 1));

    const int* entb = ent + (size_t)b * (NPATH * (L + 1));
    const int* midb = mid + (size_t)b * (NPATH * L);
    for (int i = tid; i < NPATH * (L + 1); i += 256) s_ent[i] = entb[i];
    for (int i = tid; i < NPATH * L; i += 256) s_mid[i] = midb[i];
    if (tid < NPATH) s_cnt[tid] = counts[(size_t)b * NPATH + tid];
    __syncthreads();

    float4 Wr[3], Br[3];
#pragma unroll
    for (int m = 0; m < 3; ++m) {
        Wr[m] = W4[m * 32 + dl];
        Br[m] = B4[m * 32 + dl];
    }

    float4 n1 = make_float4(0.f, 0.f, 0.f, 0.f);
    float4 n2 = make_float4(0.f, 0.f, 0.f, 0.f);

#pragma unroll 2
    for (int j = 0; j < NPATH / 8; ++j) {
        const int p = pq + 8 * j;
        int ei[L + 1], mi[L];
#pragma unroll
        for (int i = 0; i <= L; ++i) ei[i] = s_ent[p * (L + 1) + i];
#pragma unroll
        for (int i = 0; i < L; ++i) mi[i] = s_mid[p * L + i];

        float4 e[L + 1];
#pragma unroll
        for (int i = 0; i <= L; ++i) e[i] = E4[(size_t)ei[i] * 32 + dl];
        const float c = s_cnt[p];

        float4 x = e[0];
#pragma unroll
        for (int i = 0; i < L; ++i)
            x = chain_step(x, e[i + 1], sel3q(Wr, mi[i]), sel3q(Br, mi[i]));

        const float4 yl = e[L];
        float4 x2 = yl;
#pragma unroll
        for (int i = L - 1; i >= 0; --i)
            x2 = chain_step(x2, yl, sel3q(Wr, mi[i]), sel3q(Br, mi[i]));

        n1.x = fmaf(c, x.x, n1.x); n1.y = fmaf(c, x.y, n1.y);
        n1.z = fmaf(c, x.z, n1.z); n1.w = fmaf(c, x.w, n1.w);
        n2.x = fmaf(c, x2.x, n2.x); n2.y = fmaf(c, x2.y, n2.y);
        n2.z = fmaf(c, x2.z, n2.z); n2.w = fmaf(c, x2.w, n2.w);
    }

    s_red[(pq * 2 + 0) * 32 + dl] = n1;
    s_red[(pq * 2 + 1) * 32 + dl] = n2;
    __syncthreads();
    if (tid < 64) {
        const int half = tid >> 5, dq = tid & 31;
        float4 a = s_red[(0 * 2 + half) * 32 + dq];
#pragma unroll
        for (int q = 1; q < 8; ++q) {
            float4 t = s_red[(q * 2 + half) * 32 + dq];
            a.x += t.x; a.y += t.y; a.z += t.z; a.w += t.w;
        }
        float den = 0.f;
#pragma unroll
        for (int p = 0; p < NPATH; ++p) den += s_cnt[p];
        const float inv = 1.f / den;
        a.x *= inv; a.y *= inv; a.z *= inv; a.w *= inv;
        float4* hb = (float4*)(h + (size_t)b * DIN + gcol);
        hb[half * 32 + dq] = a;
    }
}

__global__ __launch_bounds__(256) void groups_kernel(
    const int* __restrict__ e1, const int* __restrict__ m1, const float* __restrict__ c1,
    const int* __restrict__ e2, const int* __restrict__ m2, const float* __restrict__ c2,
    const int* __restrict__ e3, const int* __restrict__ m3, const float* __restrict__ c3,
    const float* __restrict__ E, const float* __restrict__ W, const float* __restrict__ Bm,
    float* __restrict__ h)
{
    __shared__ int s_idx[NPATH * 7 + NPATH];
    __shared__ float4 s_red[8 * 2 * 32];
    const float4* E4 = (const float4*)E;
    const float4* W4 = (const float4*)W;
    const float4* B4 = (const float4*)Bm;
    const int g = blockIdx.y;
    if (g == 0)      group_body<1>(e1, m1, c1, E4, W4, B4, h, 0,   s_idx, s_red);
    else if (g == 1) group_body<2>(e2, m2, c2, E4, W4, B4, h, 256, s_idx, s_red);
    else             group_body<3>(e3, m3, c3, E4, W4, B4, h, 512, s_idx, s_red);
}

// Fused MLP head, LDS-staged. 8 rows/block -> 512 blocks, 256 threads.
// Stage the contiguous 8x768 h tile into LDS (one latency exposure), then
// layer 1 reads h via LDS broadcast + coalesced W1 loads.
#define MROWS 8
__global__ __launch_bounds__(256) void mlp_kernel(
    const float* __restrict__ h,
    const float* __restrict__ W1, const float* __restrict__ b1,
    const float* __restrict__ W2, const float* __restrict__ b2,
    const float* __restrict__ W3, const float* __restrict__ b3,
    float* __restrict__ out)
{
    const int tid = threadIdx.x;
    const int c = tid & 127;          // layer-1 column
    const int rh = tid >> 7;          // 0..1, owns rows rh*4 .. rh*4+3
    const int row0 = blockIdx.x * MROWS;

    __shared__ float hs[MROWS * DIN];     // 24 KB, rows contiguous
    {
        const float4* src = (const float4*)(h + (size_t)row0 * DIN);
        float4* dst = (float4*)hs;
#pragma unroll
        for (int i = 0; i < (MROWS * DIN / 4) / 256; ++i)
            dst[tid + i * 256] = src[tid + i * 256];   // 6 coalesced float4 / thread
    }
    __syncthreads();

    float acc[4];
    const float bias1 = b1[c];
#pragma unroll
    for (int r = 0; r < 4; ++r) acc[r] = bias1;

    const float* hrow = hs + rh * 4 * DIN;
    for (int k0 = 0; k0 < DIN; k0 += 4) {
        // 4 coalesced W1 dwords + 4 LDS b128 broadcasts + 16 FMA
        float w0 = W1[(k0 + 0) * C1 + c];
        float w1 = W1[(k0 + 1) * C1 + c];
        float w2 = W1[(k0 + 2) * C1 + c];
        float w3 = W1[(k0 + 3) * C1 + c];
#pragma unroll
        for (int r = 0; r < 4; ++r) {
            const float4 hq = *(const float4*)(hrow + r * DIN + k0);
            acc[r] = fmaf(hq.x, w0, acc[r]);
            acc[r] = fmaf(hq.y, w1, acc[r]);
            acc[r] = fmaf(hq.z, w2, acc[r]);
            acc[r] = fmaf(hq.w, w3, acc[r]);
        }
    }

    __shared__ float h1[MROWS][C1];
#pragma unroll
    for (int r = 0; r < 4; ++r) h1[rh * 4 + r][c] = fmaxf(acc[r], 0.f);
    __syncthreads();

    // layer 2: 8 rows x 32 cols = 256 outputs, one per thread
    __shared__ float h2[MROWS][C2];
    {
        const int r = tid >> 5;           // 0..7
        const int c2 = tid & 31;
        float a = b2[c2];
#pragma unroll
        for (int k = 0; k < C1; ++k)
            a = fmaf(h1[r][k], W2[k * C2 + c2], a);
        h2[r][c2] = fmaxf(a, 0.f);
    }
    __syncthreads();

    // layer 3
    if (tid < MROWS) {
        float a = b3[0];
#pragma unroll
        for (int k = 0; k < C2; ++k)
            a = fmaf(h2[tid][k], W3[k], a);
        out[row0 + tid] = a;
    }
}

extern "C" void kernel_launch(void* const* d_in, const int* in_sizes, int n_in,
                              void* d_out, int out_size, void* d_ws, size_t ws_size,
                              hipStream_t stream) {
    const int*   ent1 = (const int*)d_in[0];
    const int*   mid1 = (const int*)d_in[1];
    const float* cnt1 = (const float*)d_in[2];
    const int*   ent2 = (const int*)d_in[3];
    const int*   mid2 = (const int*)d_in[4];
    const float* cnt2 = (const float*)d_in[5];
    const int*   ent3 = (const int*)d_in[6];
    const int*   mid3 = (const int*)d_in[7];
    const float* cnt3 = (const float*)d_in[8];
    const float* E    = (const float*)d_in[9];
    const float* W    = (const float*)d_in[10];
    const float* Bm   = (const float*)d_in[11];
    const float* W1   = (const float*)d_in[12];
    const float* b1   = (const float*)d_in[13];
    const float* W2   = (const float*)d_in[14];
    const float* b2   = (const float*)d_in[15];
    const float* W3   = (const float*)d_in[16];
    const float* b3   = (const float*)d_in[17];

    float* h = (float*)d_ws;   // [BATCH, 768]
    float* out = (float*)d_out;

    dim3 ggrid(BATCH, 3);
    groups_kernel<<<ggrid, 256, 0, stream>>>(ent1, mid1, cnt1, ent2, mid2, cnt2,
                                             ent3, mid3, cnt3, E, W, Bm, h);
    mlp_kernel<<<BATCH / MROWS, 256, 0, stream>>>(h, W1, b1, W2, b2, W3, b3, out);
}